// Round 3
// baseline (546.220 us; speedup 1.0000x reference)
//
#include <hip/hip_runtime.h>
#include <math.h>

#define NB   1024
#define LI   2
#define LH   256
#define LQ   64
#define KK   40
#define IMG  16

// ---------------------------------------------------------------------------
// prep: collapse h-conv + 1x1 r-conv into a single effective 2->1 3x3 conv.
// W_eff[i][ky][kx] = sum_c r_w[c] * h_w[c][i][ky][kx]   (18 floats)
// b_eff            = sum_c r_w[c] * h_b[c]              (1 float)
// ---------------------------------------------------------------------------
__global__ void prep_kernel(const float* __restrict__ h_w,
                            const float* __restrict__ h_b,
                            const float* __restrict__ r_w,
                            float* __restrict__ weff) {
    int t = threadIdx.x;
    if (t < 19) {
        float acc = 0.f;
        if (t < 18) {
            for (int c = 0; c < LH; ++c)
                acc += r_w[c] * h_w[c * 18 + t];
        } else {
            for (int c = 0; c < LH; ++c)
                acc += r_w[c] * h_b[c];
        }
        weff[t] = acc;
    }
}

// ---------------------------------------------------------------------------
// main: one block per batch image. 256 threads = 16x16 pixels.
// qr[64] in registers; v in double-buffered zero-bordered 18x18 LDS.
// ---------------------------------------------------------------------------
__global__ __launch_bounds__(256) void vin_kernel(
    const float* __restrict__ X,     const float* __restrict__ S1,
    const float* __restrict__ S2,    const float* __restrict__ gamma,
    const float* __restrict__ q_w,   const float* __restrict__ w,
    const float* __restrict__ fc1,   const float* __restrict__ fc2,
    const float* __restrict__ fc3,   const float* __restrict__ weff,
    float* __restrict__ out) {
    __shared__ float rpad[18 * 18];
    __shared__ float vbuf[2][18 * 18];
    __shared__ float vout[580];
    __shared__ float l1[100];
    __shared__ float l2[52];

    const int b = blockIdx.x;
    const int t = threadIdx.x;
    const int x = t & 15;
    const int y = t >> 4;

    // zero whole padded buffers (borders must be 0 for SAME padding)
    for (int idx = t; idx < 18 * 18; idx += 256) {
        rpad[idx]    = 0.f;
        vbuf[0][idx] = 0.f;
        vbuf[1][idx] = 0.f;
    }
    __syncthreads();

    // ---- r = conv3x3(X, W_eff) + b_eff ----
    const float* Xb = X + (size_t)b * (LI * IMG * IMG);
    float racc = weff[18];
#pragma unroll
    for (int i = 0; i < LI; ++i) {
#pragma unroll
        for (int ky = 0; ky < 3; ++ky) {
            int yy = y + ky - 1;
#pragma unroll
            for (int kx = 0; kx < 3; ++kx) {
                int xx = x + kx - 1;
                if (yy >= 0 && yy < IMG && xx >= 0 && xx < IMG)
                    racc += weff[i * 9 + ky * 3 + kx] * Xb[i * 256 + yy * 16 + xx];
            }
        }
    }
    rpad[(y + 1) * 18 + (x + 1)] = racc;
    __syncthreads();

    // ---- qr = conv3x3(r, q_w), 64 channels, kept in registers ----
    float p[9];
#pragma unroll
    for (int ky = 0; ky < 3; ++ky)
#pragma unroll
        for (int kx = 0; kx < 3; ++kx)
            p[ky * 3 + kx] = rpad[(y + ky) * 18 + (x + kx)];

    float qr[64];
    float v0 = -1e30f;
#pragma unroll
    for (int o = 0; o < 64; ++o) {
        float acc = 0.f;
#pragma unroll
        for (int k2 = 0; k2 < 9; ++k2)
            acc += q_w[o * 9 + k2] * p[k2];
        qr[o] = acc;
        v0 = fmaxf(v0, acc);
    }
    vbuf[0][(y + 1) * 18 + (x + 1)] = v0;
    __syncthreads();

    // ---- K-1 = 39 value-iteration steps ----
    int cur = 0;
    for (int it = 0; it < KK - 1; ++it) {
#pragma unroll
        for (int ky = 0; ky < 3; ++ky)
#pragma unroll
            for (int kx = 0; kx < 3; ++kx)
                p[ky * 3 + kx] = vbuf[cur][(y + ky) * 18 + (x + kx)];
        float vm = -1e30f;
#pragma unroll
        for (int o = 0; o < 64; ++o) {
            float acc = qr[o];
#pragma unroll
            for (int k2 = 0; k2 < 9; ++k2)
                acc += w[o * 9 + k2] * p[k2];
            vm = fmaxf(vm, acc);
        }
        vbuf[cur ^ 1][(y + 1) * 18 + (x + 1)] = vm;
        cur ^= 1;
        __syncthreads();
    }

    // ---- final q = qr + conv3x3(v, w) (no max), overwrite qr regs ----
#pragma unroll
    for (int ky = 0; ky < 3; ++ky)
#pragma unroll
        for (int kx = 0; kx < 3; ++kx)
            p[ky * 3 + kx] = vbuf[cur][(y + ky) * 18 + (x + kx)];
#pragma unroll
    for (int o = 0; o < 64; ++o) {
        float acc = qr[o];
#pragma unroll
        for (int k2 = 0; k2 < 9; ++k2)
            acc += w[o * 9 + k2] * p[k2];
        qr[o] = acc;
    }

    // ---- gather 3x3 neighborhood at (s2, s1) ----
    float s1v = S1[b], s2v = S2[b];
    int s1g = (int)floorf(s1v);
    s1g = min(max(s1g, 0), IMG - 1);
    int s2g = IMG - 1 - (int)floorf(s2v);
    s2g = min(max(s2g, 0), IMG - 1);
    int s1i[3] = {max(s1g - 1, 0), s1g, min(s1g + 1, IMG - 1)};
    int s2i[3] = {max(s2g - 1, 0), s2g, min(s2g + 1, IMG - 1)};
#pragma unroll
    for (int i = 0; i < 3; ++i)
#pragma unroll
        for (int j = 0; j < 3; ++j)
            if (x == s1i[i] && y == s2i[j]) {
#pragma unroll
                for (int o = 0; o < 64; ++o)
                    vout[(i * 3 + j) * 64 + o] = qr[o];
            }
    if (t == 0) {
        vout[576] = s1v;
        vout[577] = s2v;
        vout[578] = gamma[b];
    }
    __syncthreads();

    // ---- MLP: 579 -> 100 -> 50 -> 1 ----
    if (t < 100) {
        float acc = 0.f;
        for (int k2 = 0; k2 < 579; ++k2)
            acc += fc1[t * 579 + k2] * vout[k2];
        l1[t] = fmaxf(acc, 0.f);
    }
    __syncthreads();
    if (t < 50) {
        float acc = 0.f;
        for (int k2 = 0; k2 < 100; ++k2)
            acc += fc2[t * 100 + k2] * l1[k2];
        l2[t] = fmaxf(acc, 0.f);
    }
    __syncthreads();
    if (t == 0) {
        float acc = 0.f;
        for (int k2 = 0; k2 < 50; ++k2)
            acc += fc3[k2] * l2[k2];
        out[b] = acc;
    }
}

extern "C" void kernel_launch(void* const* d_in, const int* in_sizes, int n_in,
                              void* d_out, int out_size, void* d_ws, size_t ws_size,
                              hipStream_t stream) {
    const float* X     = (const float*)d_in[0];
    const float* S1    = (const float*)d_in[1];
    const float* S2    = (const float*)d_in[2];
    const float* gamma = (const float*)d_in[3];
    const float* h_w   = (const float*)d_in[4];
    const float* h_b   = (const float*)d_in[5];
    const float* r_w   = (const float*)d_in[6];
    const float* q_w   = (const float*)d_in[7];
    const float* w     = (const float*)d_in[8];
    const float* fc1   = (const float*)d_in[9];
    const float* fc2   = (const float*)d_in[10];
    const float* fc3   = (const float*)d_in[11];
    float* weff = (float*)d_ws;
    float* outp = (float*)d_out;

    prep_kernel<<<1, 64, 0, stream>>>(h_w, h_b, r_w, weff);
    vin_kernel<<<NB, 256, 0, stream>>>(X, S1, S2, gamma, q_w, w, fc1, fc2, fc3,
                                       weff, outp);
}